// Round 20
// baseline (125.654 us; speedup 1.0000x reference)
//
#include <hip/hip_runtime.h>
#include <hip/hip_bf16.h>

#define KW   7
#define CIN  64
#define COUT 64
#define HH   64
#define WW   64
#define BB   4
#define HW   (HH * WW)

#define NCH  4             // channels per block
#define TRO  8             // output rows per block
#define SRO  (TRO + 6)     // 14 staged k/v rows
#define LWROW 36           // W LDS row stride (dwords)
#define LOG2E 1.44269504088896f

// ===== DIAGNOSTIC ROUND: phase 1 repeated REP1x behind an opaque VGPR
// offset (defeats cross-rep CSE; every rep re-loads x and rewrites identical
// LDS values — idempotent). Phase 2 runs once. Purpose: measure warm ph1
// marginal cost and capture ph1-dominated counters above the fill cutoff. =====
#define REP1 16

typedef __attribute__((ext_vector_type(8))) short  short8v;   // 8 bf16
typedef __attribute__((ext_vector_type(4))) float  f32x4;
typedef __attribute__((ext_vector_type(4))) unsigned u32x4;

// RNE f32-pair -> packed bf16 via HW v_cvt_pk_bf16_f32
__device__ __forceinline__ unsigned pack2(float lo, float hi) {
    float2 f;  f.x = lo;  f.y = hi;
    __hip_bfloat162 h = __float22bfloat162_rn(f);
    unsigned u;
    __builtin_memcpy(&u, &h, sizeof(u));
    return u;
}

template <bool USE_H>
__device__ __forceinline__ void attn_pair(
    const float2 (*kvp)[70], int tx, int r0,
    float q20, float q21, const float qadd0[KW], const float qadd1[KW],
    float& s0o, float& a0o, float& s1o, float& a1o)
{
    float s0 = 0.f, a0 = 0.f, s1 = 0.f, a1 = 0.f;
    #pragma unroll
    for (int rr = 0; rr < 8; ++rr) {          // staged rows r0 .. r0+7
        float2 kvx[KW];
        #pragma unroll
        for (int j = 0; j < KW; ++j) kvx[j] = kvp[r0 + rr][tx + j];

        if (rr <= 6) {                         // out row r0: window row i = rr
            #pragma unroll
            for (int j = 0; j < KW; ++j) {
                const float e = __builtin_amdgcn_exp2f(
                    fmaf(q20, kvx[j].x, USE_H ? qadd0[rr] : qadd0[j]));
                s0 += e;
                a0 = fmaf(e, kvx[j].y, a0);
            }
        }
        if (rr >= 1) {                         // out row r0+1: window row rr-1
            #pragma unroll
            for (int j = 0; j < KW; ++j) {
                const float e = __builtin_amdgcn_exp2f(
                    fmaf(q21, kvx[j].x, USE_H ? qadd1[rr - 1] : qadd1[j]));
                s1 += e;
                a1 = fmaf(e, kvx[j].y, a1);
            }
        }
    }
    s0o = s0;  a0o = a0;  s1o = s1;  a1o = a1;
}

template <bool USE_H>
__device__ __forceinline__ void attn_half(
    const float2 (*kvp)[70], const float (*qch)[64], const float rel[KW],
    int half, int tx, int h0, size_t obase, float* __restrict__ out)
{
    #pragma unroll
    for (int rp2 = 0; rp2 < 2; ++rp2) {
        const int r0 = (half * 2 + rp2) * 2;   // local out rows r0, r0+1

        const float q20 = qch[r0][tx]     * LOG2E;
        const float q21 = qch[r0 + 1][tx] * LOG2E;
        float qadd0[KW], qadd1[KW];
        #pragma unroll
        for (int t = 0; t < KW; ++t) {
            qadd0[t] = q20 * rel[t];
            qadd1[t] = q21 * rel[t];
        }

        float s0, a0, s1, a1;
        attn_pair<USE_H>(kvp, tx, r0, q20, q21, qadd0, qadd1, s0, a0, s1, a1);

        out[obase + (size_t)(h0 + r0) * WW + tx]     = a0 * __builtin_amdgcn_rcpf(s0);
        out[obase + (size_t)(h0 + r0 + 1) * WW + tx] = a1 * __builtin_amdgcn_rcpf(s1);
    }
}

__global__ __launch_bounds__(512) void fusedK(
    const float* __restrict__ x,  const float* __restrict__ wq,
    const float* __restrict__ wk, const float* __restrict__ wv,
    const float* __restrict__ rel_h, const float* __restrict__ rel_w,
    float* __restrict__ out)
{
    __shared__ float2 kv[NCH][SRO][70];        // (k,v) interleaved, 31.4 KB
    __shared__ float  qtf[NCH][TRO][64];       // q as f32, 8 KB
    __shared__ unsigned lw[16 * LWROW];        // stacked W bf16 pairs, 2.3 KB

    const int tid  = threadIdx.x;
    const int lane = tid & 63;
    const int wid  = tid >> 6;                 // 0..7
    const int h0   = blockIdx.x * TRO;
    const int c0   = blockIdx.y * NCH;
    const int b    = blockIdx.z;

    const int col = lane & 15;
    const int lg  = lane >> 4;
    const float* xb = x + (size_t)b * CIN * HW;

    auto LOAD = [&](float (&v)[16], int t, const float* xbase) {
        const int n  = wid + t * 8;
        const int sr = n >> 2;
        const int gr = h0 - 3 + sr;            // wave-uniform
        if ((unsigned)gr >= HH) return;        // halo row: nothing to load
        const int quad = n & 3;
        const float* xp = xbase + (size_t)gr * WW + quad * 16 + col;
        #pragma unroll
        for (int kc = 0; kc < 2; ++kc)
            #pragma unroll
            for (int m = 0; m < 8; ++m)
                v[kc * 8 + m] = xp[(size_t)(kc * 32 + lg * 8 + m) * HW];
    };

    short8v afrag[2];

    auto CONSUME = [&](const float (&v)[16], int t) {
        const int n  = wid + t * 8;
        const int sr = n >> 2;
        const int gr = h0 - 3 + sr;
        if ((unsigned)gr >= HH) return;        // halo row: kv stays zero
        const int quad = n & 3;

        f32x4 acc = {0.f, 0.f, 0.f, 0.f};
        #pragma unroll
        for (int kc = 0; kc < 2; ++kc) {
            u32x4 bd;
            #pragma unroll
            for (int i = 0; i < 4; ++i)
                bd[i] = pack2(v[kc * 8 + 2 * i], v[kc * 8 + 2 * i + 1]);
            acc = __builtin_amdgcn_mfma_f32_16x16x32_bf16(
                afrag[kc], __builtin_bit_cast(short8v, bd), acc, 0, 0, 0);
        }

        const int pxc = quad * 16 + col;
        if (lg == 0) {                          // q channels c0..c0+3
            if (sr >= 3 && sr < 3 + TRO) {
                #pragma unroll
                for (int r = 0; r < 4; ++r) qtf[r][sr - 3][pxc] = acc[r];
            }
        } else if (lg == 1) {                   // k
            #pragma unroll
            for (int r = 0; r < 4; ++r) kv[r][sr][3 + pxc].x = acc[r];
        } else if (lg == 2) {                   // v
            #pragma unroll
            for (int r = 0; r < 4; ++r) kv[r][sr][3 + pxc].y = acc[r];
        }
    };

    {   // zero-fill kv (halo rows/cols must stay exactly 0)
        float2* kvf = &kv[0][0][0];
        for (int i = tid; i < NCH * SRO * 70; i += 512)
            kvf[i] = make_float2(0.f, 0.f);
    }
    {   // stage stacked W (12 real rows + 4 zero): 512 slots, 1/thread
        const float* wsel[3] = {wq, wk, wv};
        const int r  = tid >> 5;               // 0..15
        const int dw = tid & 31;
        unsigned v = 0u;
        if (r < 12) {
            const float* wr = wsel[r >> 2] + (c0 + (r & 3)) * CIN + dw * 2;
            v = pack2(wr[0], wr[1]);
        }
        lw[r * LWROW + dw] = v;
    }
    __syncthreads();

    #pragma unroll
    for (int kc = 0; kc < 2; ++kc)
        afrag[kc] = *(const short8v*)&lw[col * LWROW + kc * 16 + lg * 4];

    // ---- Phase 1 repeated REP1x (diagnostic) ----
    float xv0[16], xv1[16];
    #pragma unroll 1
    for (int rep = 0; rep < REP1; ++rep) {
        int xoff = 0;
        asm volatile("" : "+v"(xoff));         // opaque: defeats cross-rep CSE
        const float* xr = xb + xoff;
        LOAD(xv0, 0, xr);
        LOAD(xv1, 1, xr);
        CONSUME(xv0, 0);  LOAD(xv0, 2, xr);
        CONSUME(xv1, 1);  LOAD(xv1, 3, xr);
        CONSUME(xv0, 2);  LOAD(xv0, 4, xr);
        CONSUME(xv1, 3);  LOAD(xv1, 5, xr);
        CONSUME(xv0, 4);  LOAD(xv0, 6, xr);
        CONSUME(xv1, 5);
        CONSUME(xv0, 6);
    }
    __syncthreads();

    // ---- Phase 2: 7x7 local attention (unchanged, run once) ----
    const int tx   = lane;
    const int ch   = wid >> 1;                 // 0..3
    const int half = wid & 1;
    const int o    = c0 + ch;
    const bool use_h = (o < COUT / 2);         // wave-uniform

    float rel[KW];
    {
        const float* rp_ = use_h ? (rel_h + o * KW) : (rel_w + (o - COUT / 2) * KW);
        #pragma unroll
        for (int t = 0; t < KW; ++t) rel[t] = rp_[t];
    }
    const size_t obase = ((size_t)b * COUT + o) * HW;

    if (use_h) attn_half<true >(kv[ch], qtf[ch], rel, half, tx, h0, obase, out);
    else       attn_half<false>(kv[ch], qtf[ch], rel, half, tx, h0, obase, out);
}

extern "C" void kernel_launch(void* const* d_in, const int* in_sizes, int n_in,
                              void* d_out, int out_size, void* d_ws, size_t ws_size,
                              hipStream_t stream) {
    const float* x     = (const float*)d_in[0];
    const float* wq    = (const float*)d_in[1];
    const float* wk    = (const float*)d_in[2];
    const float* wv    = (const float*)d_in[3];
    const float* rel_h = (const float*)d_in[4];
    const float* rel_w = (const float*)d_in[5];
    float* out = (float*)d_out;

    dim3 grid(HH / TRO, COUT / NCH, BB);       // (8, 16, 4) = 512 blocks
    fusedK<<<grid, 512, 0, stream>>>(x, wq, wk, wv, rel_h, rel_w, out);
}

// Round 21
// 22.018 us; speedup vs baseline: 5.7068x; 5.7068x over previous
//
#include <hip/hip_runtime.h>
#include <hip/hip_bf16.h>

#define KW   7
#define CIN  64
#define COUT 64
#define HH   64
#define WW   64
#define BB   4
#define HW   (HH * WW)

#define NCH  8             // channels per block (halves x re-read vs NCH=4)
#define TRO  4             // output rows per block
#define SRO  (TRO + 6)     // 10 staged k/v rows
#define LWROW 36           // W LDS row stride (dwords)
#define LOG2E 1.44269504088896f

typedef __attribute__((ext_vector_type(8))) short  short8v;   // 8 bf16
typedef __attribute__((ext_vector_type(4))) float  f32x4;
typedef __attribute__((ext_vector_type(4))) unsigned u32x4;

// RNE f32-pair -> packed bf16 via HW v_cvt_pk_bf16_f32
__device__ __forceinline__ unsigned pack2(float lo, float hi) {
    float2 f;  f.x = lo;  f.y = hi;
    __hip_bfloat162 h = __float22bfloat162_rn(f);
    unsigned u;
    __builtin_memcpy(&u, &h, sizeof(u));
    return u;
}

// ---------------------------------------------------------------------------
// Fused AttentionConv, NCH=8 reshape (attacks the measured ph1 term).
// R20 diagnosis: ph1_warm = 6.6us, L2-BW-bound on 117 MB of redundant x reads
// (16 o-groups x 1.75 halo). This block shape = 8 channels x 4 rows -> 84 MB
// (8 o-groups x 2.5 halo), -28% L2 traffic, 80 loads/wave vs 112.
//
// Block = 8 channels x 4 output rows x 1 batch; grid (16,8,4) = 512 blocks
// x 512 threads. LDS 57.4 KB: kv[8][10][70] f32-pairs + qtf[8][4][64] f32
// + lw (stacked W).
// Phase 1: D[32 x 640] = Wstk[32 x 64] @ x[64 x 640] per block, via
//   mfma_f32_16x16x32_bf16 (2 M-tiles x 2 kc = 4 MFMA/tile; MFMA at 4% util
//   so the extra halo MFMAs are free). Wstk rows 0-7 wq(c0..c0+7), 8-15 wk,
//   16-23 wv, 24-31 zero. A/B frags share the same lane->k map (permutation
//   cancels; R9/R13-proven). C layout m89: n=lane&15 (pixel),
//   m=(lane>>4)*4+reg. Routing: mt0 lg0/1 -> q ch 0-7 (f32 LDS, interior
//   rows only), mt0 lg2/3 -> k ch 0-7 (.x), mt1 lg0/1 -> v ch 0-7 (.y),
//   mt1 lg2/3 -> pad (no store). Halo rows outside [0,64) skipped -> kv
//   stays zero (1x1 conv of zero padding, no bias = 0).
// Phase 2 (R14-proven body, identical per-wave work): wave = one channel;
//   2 row-pairs/wave, 2-row register blocking, float2 LDS reads, no-max
//   softmax (bench-validated absmax 0.068), rel select templated.
// ---------------------------------------------------------------------------

template <bool USE_H>
__device__ __forceinline__ void attn_pair(
    const float2 (*kvp)[70], int tx, int r0,
    float q20, float q21, const float qadd0[KW], const float qadd1[KW],
    float& s0o, float& a0o, float& s1o, float& a1o)
{
    float s0 = 0.f, a0 = 0.f, s1 = 0.f, a1 = 0.f;
    #pragma unroll
    for (int rr = 0; rr < 8; ++rr) {          // staged rows r0 .. r0+7
        float2 kvx[KW];
        #pragma unroll
        for (int j = 0; j < KW; ++j) kvx[j] = kvp[r0 + rr][tx + j];

        if (rr <= 6) {                         // out row r0: window row i = rr
            #pragma unroll
            for (int j = 0; j < KW; ++j) {
                const float e = __builtin_amdgcn_exp2f(
                    fmaf(q20, kvx[j].x, USE_H ? qadd0[rr] : qadd0[j]));
                s0 += e;
                a0 = fmaf(e, kvx[j].y, a0);
            }
        }
        if (rr >= 1) {                         // out row r0+1: window row rr-1
            #pragma unroll
            for (int j = 0; j < KW; ++j) {
                const float e = __builtin_amdgcn_exp2f(
                    fmaf(q21, kvx[j].x, USE_H ? qadd1[rr - 1] : qadd1[j]));
                s1 += e;
                a1 = fmaf(e, kvx[j].y, a1);
            }
        }
    }
    s0o = s0;  a0o = a0;  s1o = s1;  a1o = a1;
}

template <bool USE_H>
__device__ __forceinline__ void attn_wave(
    const float2 (*kvp)[70], const float (*qch)[64], const float rel[KW],
    int tx, int h0, size_t obase, float* __restrict__ out)
{
    #pragma unroll
    for (int rp2 = 0; rp2 < 2; ++rp2) {        // row pairs (0,1) and (2,3)
        const int r0 = 2 * rp2;

        const float q20 = qch[r0][tx]     * LOG2E;
        const float q21 = qch[r0 + 1][tx] * LOG2E;
        float qadd0[KW], qadd1[KW];
        #pragma unroll
        for (int t = 0; t < KW; ++t) {
            qadd0[t] = q20 * rel[t];
            qadd1[t] = q21 * rel[t];
        }

        float s0, a0, s1, a1;
        attn_pair<USE_H>(kvp, tx, r0, q20, q21, qadd0, qadd1, s0, a0, s1, a1);

        out[obase + (size_t)(h0 + r0) * WW + tx]     = a0 * __builtin_amdgcn_rcpf(s0);
        out[obase + (size_t)(h0 + r0 + 1) * WW + tx] = a1 * __builtin_amdgcn_rcpf(s1);
    }
}

__global__ __launch_bounds__(512) void fusedK(
    const float* __restrict__ x,  const float* __restrict__ wq,
    const float* __restrict__ wk, const float* __restrict__ wv,
    const float* __restrict__ rel_h, const float* __restrict__ rel_w,
    float* __restrict__ out)
{
    __shared__ float2 kv[NCH][SRO][70];        // (k,v) interleaved, 44.8 KB
    __shared__ float  qtf[NCH][TRO][64];       // q as f32, 8 KB
    __shared__ unsigned lw[32 * LWROW];        // stacked W bf16 pairs, 4.6 KB

    const int tid  = threadIdx.x;
    const int lane = tid & 63;
    const int wid  = tid >> 6;                 // 0..7
    const int h0   = blockIdx.x * TRO;
    const int c0   = blockIdx.y * NCH;
    const int b    = blockIdx.z;

    const int col = lane & 15;
    const int lg  = lane >> 4;
    const float* xb = x + (size_t)b * CIN * HW;

    {   // zero-fill kv (halo rows/cols must stay exactly 0)
        float2* kvf = &kv[0][0][0];
        for (int i = tid; i < NCH * SRO * 70; i += 512)
            kvf[i] = make_float2(0.f, 0.f);
    }
    {   // stage stacked W: rows 0-7 wq, 8-15 wk, 16-23 wv (ch c0..c0+7), 24-31 zero
        const float* wsel[3] = {wq, wk, wv};
        for (int idx = tid; idx < 32 * 32; idx += 512) {
            const int r  = idx >> 5;           // 0..31
            const int dw = idx & 31;
            unsigned v = 0u;
            if (r < 24) {
                const float* wr = wsel[r >> 3] + (c0 + (r & 7)) * CIN + dw * 2;
                v = pack2(wr[0], wr[1]);
            }
            lw[r * LWROW + dw] = v;
        }
    }
    __syncthreads();

    // ---- Phase 1: MFMA projection into LDS ----
    short8v afrag[2][2];                       // [m-tile][kc]
    #pragma unroll
    for (int mt = 0; mt < 2; ++mt)
        #pragma unroll
        for (int kc = 0; kc < 2; ++kc)
            afrag[mt][kc] =
                *(const short8v*)&lw[(mt * 16 + col) * LWROW + kc * 16 + lg * 4];

    #pragma unroll
    for (int t = 0; t < 5; ++t) {              // 40 (sr,quad) tiles / 8 waves
        const int n    = wid + t * 8;
        const int sr   = n >> 2;               // staged row 0..9
        const int quad = n & 3;                // 16-px column group
        const int gr   = h0 - 3 + sr;          // wave-uniform
        if ((unsigned)gr >= HH) continue;      // halo row: kv stays zero

        const float* xp = xb + (size_t)gr * WW + quad * 16 + col;
        u32x4 bd[2];
        #pragma unroll
        for (int kc = 0; kc < 2; ++kc)
            #pragma unroll
            for (int i = 0; i < 4; ++i) {
                const int ch = kc * 32 + lg * 8 + 2 * i;
                bd[kc][i] = pack2(xp[(size_t)ch * HW], xp[(size_t)(ch + 1) * HW]);
            }

        f32x4 acc0 = {0.f, 0.f, 0.f, 0.f};
        f32x4 acc1 = {0.f, 0.f, 0.f, 0.f};
        #pragma unroll
        for (int kc = 0; kc < 2; ++kc) {
            const short8v bf = __builtin_bit_cast(short8v, bd[kc]);
            acc0 = __builtin_amdgcn_mfma_f32_16x16x32_bf16(afrag[0][kc], bf, acc0, 0, 0, 0);
            acc1 = __builtin_amdgcn_mfma_f32_16x16x32_bf16(afrag[1][kc], bf, acc1, 0, 0, 0);
        }

        const int pxc = quad * 16 + col;
        // m-tile 0: rows 0-15 = q ch 0-7 (lg0/1), k ch 0-7 (lg2/3)
        if (lg < 2) {
            if (sr >= 3 && sr < 3 + TRO) {
                #pragma unroll
                for (int r = 0; r < 4; ++r) qtf[lg * 4 + r][sr - 3][pxc] = acc0[r];
            }
        } else {
            #pragma unroll
            for (int r = 0; r < 4; ++r) kv[(lg - 2) * 4 + r][sr][3 + pxc].x = acc0[r];
        }
        // m-tile 1: rows 16-23 = v ch 0-7 (lg0/1); rows 24-31 pad (no store)
        if (lg < 2) {
            #pragma unroll
            for (int r = 0; r < 4; ++r) kv[lg * 4 + r][sr][3 + pxc].y = acc1[r];
        }
    }
    __syncthreads();

    // ---- Phase 2: 7x7 local attention (wave = one channel) ----
    const int tx = lane;
    const int o  = c0 + wid;
    const bool use_h = (o < COUT / 2);         // block-uniform (c0 multiple of 8)

    float rel[KW];
    {
        const float* rp_ = use_h ? (rel_h + o * KW) : (rel_w + (o - COUT / 2) * KW);
        #pragma unroll
        for (int t = 0; t < KW; ++t) rel[t] = rp_[t];
    }
    const size_t obase = ((size_t)b * COUT + o) * HW;

    if (use_h) attn_wave<true >(kv[wid], qtf[wid], rel, tx, h0, obase, out);
    else       attn_wave<false>(kv[wid], qtf[wid], rel, tx, h0, obase, out);
}

extern "C" void kernel_launch(void* const* d_in, const int* in_sizes, int n_in,
                              void* d_out, int out_size, void* d_ws, size_t ws_size,
                              hipStream_t stream) {
    const float* x     = (const float*)d_in[0];
    const float* wq    = (const float*)d_in[1];
    const float* wk    = (const float*)d_in[2];
    const float* wv    = (const float*)d_in[3];
    const float* rel_h = (const float*)d_in[4];
    const float* rel_w = (const float*)d_in[5];
    float* out = (float*)d_out;

    dim3 grid(HH / TRO, COUT / NCH, BB);       // (16, 8, 4) = 512 blocks
    fusedK<<<grid, 512, 0, stream>>>(x, wq, wk, wv, rel_h, rel_w, out);
}

// Round 23
// 20.092 us; speedup vs baseline: 6.2538x; 1.0959x over previous
//
#include <hip/hip_runtime.h>
#include <hip/hip_bf16.h>

#define KW   7
#define CIN  64
#define COUT 64
#define HH   64
#define WW   64
#define BB   4
#define HW   (HH * WW)

#define NCH  8             // channels per block
#define TRO  4             // output rows per block
#define SRO  (TRO + 6)     // 10 staged k/v rows
#define LWROW 36           // W LDS row stride (dwords)
#define LOG2E 1.44269504088896f

typedef __attribute__((ext_vector_type(8))) short  short8v;   // 8 bf16
typedef __attribute__((ext_vector_type(4))) float  f32x4;
typedef __attribute__((ext_vector_type(2))) float  f32x2;
typedef __attribute__((ext_vector_type(4))) unsigned u32x4;

// RNE f32-pair -> packed bf16 via HW v_cvt_pk_bf16_f32
__device__ __forceinline__ unsigned pack2(float lo, float hi) {
    float2 f;  f.x = lo;  f.y = hi;
    __hip_bfloat162 h = __float22bfloat162_rn(f);
    unsigned u;
    __builtin_memcpy(&u, &h, sizeof(u));
    return u;
}

// Packed f32 pair math — COMPILER-generated (R15/R22 lesson: hand-written
// VOP3P asm mis-encodes op_sel_hi; unspecified defaults to 0 = broadcast-low).
// __builtin_elementwise_fma keeps vector form so the backend can select
// v_pk_fma_f32; worst case it scalarizes (clean null, still correct).
__device__ __forceinline__ f32x2 pk_fma(f32x2 a, f32x2 b, f32x2 c) {
    return __builtin_elementwise_fma(a, b, c);
}
__device__ __forceinline__ f32x2 pk_add(f32x2 a, f32x2 b) { return a + b; }

// ---------------------------------------------------------------------------
// Fused AttentionConv — R21 geometry (22.0us best) with phase 2 packed over
// COLUMN pairs (j=0..5 as 3 f32x2 triples, j=6 scalar): 12 VALU + 7 trans
// per staged-row-output vs 21 + 7 scalar. k/v in separate LDS planes so
// (k[j],k[j+1]) / (v[j],v[j+1]) form natural register pairs.
// Phase 1 identical to R21 except k->kpl, v->vpl routing.
// ---------------------------------------------------------------------------
__device__ __forceinline__ void row_update(
    const float kx[8], const float vx[8], f32x2 q2p, float q2s,
    f32x2 qa0, f32x2 qa1, f32x2 qa2, float qa6,
    f32x2& s2, f32x2& a2, float& ssc, float& asc)
{
    f32x2 kk, vv, l2, e2;
    kk.x = kx[0]; kk.y = kx[1];
    l2 = pk_fma(q2p, kk, qa0);
    e2.x = __builtin_amdgcn_exp2f(l2.x);
    e2.y = __builtin_amdgcn_exp2f(l2.y);
    s2 = pk_add(s2, e2);
    vv.x = vx[0]; vv.y = vx[1];
    a2 = pk_fma(e2, vv, a2);

    kk.x = kx[2]; kk.y = kx[3];
    l2 = pk_fma(q2p, kk, qa1);
    e2.x = __builtin_amdgcn_exp2f(l2.x);
    e2.y = __builtin_amdgcn_exp2f(l2.y);
    s2 = pk_add(s2, e2);
    vv.x = vx[2]; vv.y = vx[3];
    a2 = pk_fma(e2, vv, a2);

    kk.x = kx[4]; kk.y = kx[5];
    l2 = pk_fma(q2p, kk, qa2);
    e2.x = __builtin_amdgcn_exp2f(l2.x);
    e2.y = __builtin_amdgcn_exp2f(l2.y);
    s2 = pk_add(s2, e2);
    vv.x = vx[4]; vv.y = vx[5];
    a2 = pk_fma(e2, vv, a2);

    const float e = __builtin_amdgcn_exp2f(fmaf(q2s, kx[6], qa6));
    ssc += e;
    asc = fmaf(e, vx[6], asc);
}

template <bool USE_H>
__device__ __forceinline__ void attn_wave(
    const float (*kpl)[70], const float (*vpl)[70], const float (*qch)[64],
    const float rel[KW], int tx, int h0, size_t obase, float* __restrict__ out)
{
    #pragma unroll
    for (int rp2 = 0; rp2 < 2; ++rp2) {        // row pairs (0,1) and (2,3)
        const int r0 = 2 * rp2;

        const float q20 = qch[r0][tx]     * LOG2E;
        const float q21 = qch[r0 + 1][tx] * LOG2E;
        f32x2 q2p0;  q2p0.x = q20;  q2p0.y = q20;
        f32x2 q2p1;  q2p1.x = q21;  q2p1.y = q21;

        float qh0[KW], qh1[KW];
        f32x2 qw0[3], qw1[3];
        float qw0s = 0.f, qw1s = 0.f;
        if (USE_H) {
            #pragma unroll
            for (int t = 0; t < KW; ++t) { qh0[t] = q20 * rel[t]; qh1[t] = q21 * rel[t]; }
        } else {
            #pragma unroll
            for (int m = 0; m < 3; ++m) {
                qw0[m].x = q20 * rel[2 * m];  qw0[m].y = q20 * rel[2 * m + 1];
                qw1[m].x = q21 * rel[2 * m];  qw1[m].y = q21 * rel[2 * m + 1];
            }
            qw0s = q20 * rel[6];
            qw1s = q21 * rel[6];
        }

        f32x2 s20 = {0.f, 0.f}, a20 = {0.f, 0.f};
        f32x2 s21 = {0.f, 0.f}, a21 = {0.f, 0.f};
        float ssc0 = 0.f, asc0 = 0.f, ssc1 = 0.f, asc1 = 0.f;

        #pragma unroll
        for (int rr = 0; rr < 8; ++rr) {       // staged rows r0 .. r0+7
            float kx[8], vx[8];
            #pragma unroll
            for (int j = 0; j < KW; ++j) {
                kx[j] = kpl[r0 + rr][tx + j];
                vx[j] = vpl[r0 + rr][tx + j];
            }
            kx[7] = 0.f; vx[7] = 0.f;

            if (rr <= 6) {                     // out0: window row i = rr
                f32x2 p0, p1, p2; float p6;
                if (USE_H) {
                    const float w = qh0[rr];
                    p0.x = w; p0.y = w; p1 = p0; p2 = p0; p6 = w;
                } else { p0 = qw0[0]; p1 = qw0[1]; p2 = qw0[2]; p6 = qw0s; }
                row_update(kx, vx, q2p0, q20, p0, p1, p2, p6, s20, a20, ssc0, asc0);
            }
            if (rr >= 1) {                     // out1: window row i = rr-1
                f32x2 p0, p1, p2; float p6;
                if (USE_H) {
                    const float w = qh1[rr - 1];
                    p0.x = w; p0.y = w; p1 = p0; p2 = p0; p6 = w;
                } else { p0 = qw1[0]; p1 = qw1[1]; p2 = qw1[2]; p6 = qw1s; }
                row_update(kx, vx, q2p1, q21, p0, p1, p2, p6, s21, a21, ssc1, asc1);
            }
        }

        const float s0 = s20.x + s20.y + ssc0;
        const float a0 = a20.x + a20.y + asc0;
        const float s1 = s21.x + s21.y + ssc1;
        const float a1 = a21.x + a21.y + asc1;
        out[obase + (size_t)(h0 + r0) * WW + tx]     = a0 * __builtin_amdgcn_rcpf(s0);
        out[obase + (size_t)(h0 + r0 + 1) * WW + tx] = a1 * __builtin_amdgcn_rcpf(s1);
    }
}

__global__ __launch_bounds__(512) void fusedK(
    const float* __restrict__ x,  const float* __restrict__ wq,
    const float* __restrict__ wk, const float* __restrict__ wv,
    const float* __restrict__ rel_h, const float* __restrict__ rel_w,
    float* __restrict__ out)
{
    __shared__ float kpl[NCH][SRO][70];        // k plane f32, 22.4 KB
    __shared__ float vpl[NCH][SRO][70];        // v plane f32, 22.4 KB
    __shared__ float qtf[NCH][TRO][64];        // q f32, 8 KB
    __shared__ unsigned lw[32 * LWROW];        // stacked W bf16 pairs, 4.6 KB

    const int tid  = threadIdx.x;
    const int lane = tid & 63;
    const int wid  = tid >> 6;                 // 0..7
    const int h0   = blockIdx.x * TRO;
    const int c0   = blockIdx.y * NCH;
    const int b    = blockIdx.z;

    const int col = lane & 15;
    const int lg  = lane >> 4;
    const float* xb = x + (size_t)b * CIN * HW;

    {   // zero-fill k/v planes (halo rows/cols must stay exactly 0)
        float* kf = &kpl[0][0][0];
        float* vf = &vpl[0][0][0];
        for (int i = tid; i < NCH * SRO * 70; i += 512) {
            kf[i] = 0.f;
            vf[i] = 0.f;
        }
    }
    {   // stage stacked W: rows 0-7 wq, 8-15 wk, 16-23 wv (ch c0..c0+7), 24-31 zero
        const float* wsel[3] = {wq, wk, wv};
        for (int idx = tid; idx < 32 * 32; idx += 512) {
            const int r  = idx >> 5;           // 0..31
            const int dw = idx & 31;
            unsigned v = 0u;
            if (r < 24) {
                const float* wr = wsel[r >> 3] + (c0 + (r & 7)) * CIN + dw * 2;
                v = pack2(wr[0], wr[1]);
            }
            lw[r * LWROW + dw] = v;
        }
    }
    __syncthreads();

    // ---- Phase 1: MFMA projection into LDS (R21-proven, kpl/vpl routing) ----
    short8v afrag[2][2];                       // [m-tile][kc]
    #pragma unroll
    for (int mt = 0; mt < 2; ++mt)
        #pragma unroll
        for (int kc = 0; kc < 2; ++kc)
            afrag[mt][kc] =
                *(const short8v*)&lw[(mt * 16 + col) * LWROW + kc * 16 + lg * 4];

    #pragma unroll
    for (int t = 0; t < 5; ++t) {              // 40 (sr,quad) tiles / 8 waves
        const int n    = wid + t * 8;
        const int sr   = n >> 2;               // staged row 0..9
        const int quad = n & 3;                // 16-px column group
        const int gr   = h0 - 3 + sr;          // wave-uniform
        if ((unsigned)gr >= HH) continue;      // halo row: planes stay zero

        const float* xp = xb + (size_t)gr * WW + quad * 16 + col;
        u32x4 bd[2];
        #pragma unroll
        for (int kc = 0; kc < 2; ++kc)
            #pragma unroll
            for (int i = 0; i < 4; ++i) {
                const int ch = kc * 32 + lg * 8 + 2 * i;
                bd[kc][i] = pack2(xp[(size_t)ch * HW], xp[(size_t)(ch + 1) * HW]);
            }

        f32x4 acc0 = {0.f, 0.f, 0.f, 0.f};
        f32x4 acc1 = {0.f, 0.f, 0.f, 0.f};
        #pragma unroll
        for (int kc = 0; kc < 2; ++kc) {
            const short8v bf = __builtin_bit_cast(short8v, bd[kc]);
            acc0 = __builtin_amdgcn_mfma_f32_16x16x32_bf16(afrag[0][kc], bf, acc0, 0, 0, 0);
            acc1 = __builtin_amdgcn_mfma_f32_16x16x32_bf16(afrag[1][kc], bf, acc1, 0, 0, 0);
        }

        const int pxc = quad * 16 + col;
        // m-tile 0: rows 0-15 = q ch 0-7 (lg0/1), k ch 0-7 (lg2/3)
        if (lg < 2) {
            if (sr >= 3 && sr < 3 + TRO) {
                #pragma unroll
                for (int r = 0; r < 4; ++r) qtf[lg * 4 + r][sr - 3][pxc] = acc0[r];
            }
        } else {
            #pragma unroll
            for (int r = 0; r < 4; ++r) kpl[(lg - 2) * 4 + r][sr][3 + pxc] = acc0[r];
        }
        // m-tile 1: rows 16-23 = v ch 0-7 (lg0/1); rows 24-31 pad (no store)
        if (lg < 2) {
            #pragma unroll
            for (int r = 0; r < 4; ++r) vpl[lg * 4 + r][sr][3 + pxc] = acc1[r];
        }
    }
    __syncthreads();

    // ---- Phase 2: 7x7 local attention (wave = one channel) ----
    const int tx = lane;
    const int o  = c0 + wid;
    const bool use_h = (o < COUT / 2);         // block-uniform

    float rel[KW];
    {
        const float* rp_ = use_h ? (rel_h + o * KW) : (rel_w + (o - COUT / 2) * KW);
        #pragma unroll
        for (int t = 0; t < KW; ++t) rel[t] = rp_[t];
    }
    const size_t obase = ((size_t)b * COUT + o) * HW;

    if (use_h) attn_wave<true >(kpl[wid], vpl[wid], qtf[wid], rel, tx, h0, obase, out);
    else       attn_wave<false>(kpl[wid], vpl[wid], qtf[wid], rel, tx, h0, obase, out);
}

extern "C" void kernel_launch(void* const* d_in, const int* in_sizes, int n_in,
                              void* d_out, int out_size, void* d_ws, size_t ws_size,
                              hipStream_t stream) {
    const float* x     = (const float*)d_in[0];
    const float* wq    = (const float*)d_in[1];
    const float* wk    = (const float*)d_in[2];
    const float* wv    = (const float*)d_in[3];
    const float* rel_h = (const float*)d_in[4];
    const float* rel_w = (const float*)d_in[5];
    float* out = (float*)d_out;

    dim3 grid(HH / TRO, COUT / NCH, BB);       // (16, 8, 4) = 512 blocks
    fusedK<<<grid, 512, 0, stream>>>(x, wq, wk, wv, rel_h, rel_w, out);
}